// Round 1
// baseline (400.539 us; speedup 1.0000x reference)
//
#include <hip/hip_runtime.h>
#include <cstdint>

typedef __bf16 bf16x8 __attribute__((ext_vector_type(8)));
typedef float f32x16 __attribute__((ext_vector_type(16)));

#define LOG2E 1.44269504088896340736f

static __device__ __forceinline__ ushort f2bf(float f) {
  uint u = __builtin_bit_cast(uint, f);
  u = u + 0x7FFFu + ((u >> 16) & 1u);   // RNE
  return (ushort)(u >> 16);
}

static __device__ __forceinline__ uint cvtpk_bf16(float lo, float hi) {
  uint r;
  asm("v_cvt_pk_bf16_f32 %0, %1, %2" : "=v"(r) : "v"(lo), "v"(hi));
  return r;
}

static __device__ __forceinline__ void plswap(uint& a, uint& b) {
  asm("v_permlane32_swap_b32 %0, %1" : "+v"(a), "+v"(b));
}

#if __has_builtin(__builtin_amdgcn_exp2f)
#define EXP2(x) __builtin_amdgcn_exp2f(x)
#else
#define EXP2(x) exp2f(x)
#endif

// ---------------------------------------------------------------------------
// Kernel 1: q/k/v projections (1x1 conv == GEMM over channels), fp32 -> bf16.
// q rows are pre-scaled by log2(e) so attention softmax runs in exp2 domain.
// Block: 256 thr; tile 64 d-rows x 256 n; K=256 in chunks of 32.
// grid = (16 n-tiles, 8 batch, 5 d-tiles) ; d-tile 0 = q(0..31)+k(32..63),
// d-tiles 1..4 = v rows.
// ---------------------------------------------------------------------------
__global__ __launch_bounds__(256, 2) void proj_qkv(
    const float* __restrict__ x,
    const float* __restrict__ Wq, const float* __restrict__ bq,
    const float* __restrict__ Wk, const float* __restrict__ bk,
    const float* __restrict__ Wv, const float* __restrict__ bv,
    ushort* __restrict__ qo, ushort* __restrict__ ko, ushort* __restrict__ vo)
{
  __shared__ float xs[32][256];   // [c][n]
  __shared__ float wt[32][64];    // [c][d] (transposed W chunk)

  const int tid = threadIdx.x;
  const int nt = blockIdx.x, b = blockIdx.y, dt = blockIdx.z;
  const int n0 = nt * 256;
  const int nthr = tid & 31;      // 32 n-groups (two 4-wide slots: 4*nthr, 4*nthr+128)
  const int dthr = tid >> 5;      // 8 d-groups of 8 rows

  float acc[8][8];
#pragma unroll
  for (int i = 0; i < 8; ++i)
#pragma unroll
    for (int j = 0; j < 8; ++j) acc[i][j] = 0.f;

  const float* xb = x + (size_t)b * 256 * 4096;

  for (int kc = 0; kc < 8; ++kc) {
    const int c0 = kc * 32;
    __syncthreads();
    // stage x chunk [32][256]
#pragma unroll
    for (int r = 0; r < 8; ++r) {
      int id = r * 256 + tid;
      int c = id >> 6, pos = (id & 63) * 4;
      float4 v = *(const float4*)(xb + (size_t)(c0 + c) * 4096 + n0 + pos);
      *(float4*)&xs[c][pos] = v;
    }
    // stage W^T chunk [32][64]
#pragma unroll
    for (int r = 0; r < 2; ++r) {
      int id = r * 256 + tid;
      int d = id >> 3, c4 = (id & 7) * 4;
      int grow = dt * 64 + d;
      const float* wrow;
      float scale = 1.f;
      if (dt == 0) {
        if (grow < 32) { wrow = Wq + (size_t)grow * 256; scale = LOG2E; }
        else           { wrow = Wk + (size_t)(grow - 32) * 256; }
      } else {
        wrow = Wv + (size_t)(grow - 64) * 256;
      }
      float4 v = *(const float4*)(wrow + c0 + c4);
      wt[c4 + 0][d] = v.x * scale;
      wt[c4 + 1][d] = v.y * scale;
      wt[c4 + 2][d] = v.z * scale;
      wt[c4 + 3][d] = v.w * scale;
    }
    __syncthreads();

#pragma unroll
    for (int cc = 0; cc < 32; ++cc) {
      float4 xv0 = *(const float4*)&xs[cc][nthr * 4];
      float4 xv1 = *(const float4*)&xs[cc][nthr * 4 + 128];
      float4 wv0 = *(const float4*)&wt[cc][dthr * 8];
      float4 wv1 = *(const float4*)&wt[cc][dthr * 8 + 4];
      float wr[8] = {wv0.x, wv0.y, wv0.z, wv0.w, wv1.x, wv1.y, wv1.z, wv1.w};
      float xr[8] = {xv0.x, xv0.y, xv0.z, xv0.w, xv1.x, xv1.y, xv1.z, xv1.w};
#pragma unroll
      for (int dd = 0; dd < 8; ++dd)
#pragma unroll
        for (int nn = 0; nn < 8; ++nn)
          acc[dd][nn] = fmaf(wr[dd], xr[nn], acc[dd][nn]);
    }
  }

  // epilogue: + bias, convert to bf16, store
#pragma unroll
  for (int dd = 0; dd < 8; ++dd) {
    int d = dthr * 8 + dd;
    int grow = dt * 64 + d;
    ushort* dst;
    float bias;
    if (dt == 0) {
      if (grow < 32) { dst = qo + ((size_t)b * 32 + grow) * 4096; bias = bq[grow] * LOG2E; }
      else { dst = ko + ((size_t)b * 32 + (grow - 32)) * 4096; bias = bk[grow - 32]; }
    } else {
      int vr = grow - 64;
      dst = vo + ((size_t)b * 256 + vr) * 4096; bias = bv[vr];
    }
    ushort4 w0, w1;
    w0.x = f2bf(acc[dd][0] + bias); w0.y = f2bf(acc[dd][1] + bias);
    w0.z = f2bf(acc[dd][2] + bias); w0.w = f2bf(acc[dd][3] + bias);
    w1.x = f2bf(acc[dd][4] + bias); w1.y = f2bf(acc[dd][5] + bias);
    w1.z = f2bf(acc[dd][6] + bias); w1.w = f2bf(acc[dd][7] + bias);
    *(ushort4*)(dst + n0 + nthr * 4) = w0;
    *(ushort4*)(dst + n0 + nthr * 4 + 128) = w1;
  }
}

// ---------------------------------------------------------------------------
// Kernel 2: fused flash attention + residual.
// Block = 128 thr (2 waves), each wave owns 32 query columns (m).
// Per iteration: 32 keys. Swapped QK^T (S^T = mfma(K,Q)) -> per-lane softmax;
// P packed to bf16 in-register (cvt_pk + permlane32_swap); PV as O^T = V P^T.
// K/V tiles staged in LDS with 80B row stride (bank-conflict-free b128 reads),
// global loads for tile t+1 issued before compute of tile t.
// ---------------------------------------------------------------------------
__global__ __launch_bounds__(128, 1) void attn_fused(
    const ushort* __restrict__ qs, const ushort* __restrict__ ko,
    const ushort* __restrict__ vo, const float* __restrict__ x,
    const float* __restrict__ gamma, float* __restrict__ out)
{
  __shared__ __align__(16) ushort kT[32 * 40];   // [key n][d], stride 40 ushorts = 80B
  __shared__ __align__(16) ushort vS[256 * 40];  // [c][n],    stride 40 ushorts = 80B

  const int wg = blockIdx.x;                     // 0..511
  const int swz = (wg & 7) * 64 + (wg >> 3);     // XCD-contiguous: 1 batch per XCD
  const int b = swz >> 6, mt = swz & 63;
  const int tid = threadIdx.x;
  const int wave = tid >> 6, lane = tid & 63;
  const int l31 = lane & 31, hi = lane >> 5;
  const int m = mt * 64 + wave * 32 + l31;

  // resident Q B-frags: qf[j] holds q[j*16 + 8*hi + i][m], i=0..7
  const ushort* qcol = qs + (size_t)b * 32 * 4096 + m;
  bf16x8 qf0, qf1;
  {
    union { ushort s[8]; bf16x8 v; } u0, u1;
#pragma unroll
    for (int i = 0; i < 8; ++i) {
      u0.s[i] = qcol[(size_t)(8 * hi + i) * 4096];
      u1.s[i] = qcol[(size_t)(16 + 8 * hi + i) * 4096];
    }
    qf0 = u0.v; qf1 = u1.v;
  }

  const ushort* vb = vo + (size_t)b * 256 * 4096;
  const ushort* kb = ko + (size_t)b * 32 * 4096;

  f32x16 acc[8];
#pragma unroll
  for (int t = 0; t < 8; ++t)
#pragma unroll
    for (int r = 0; r < 16; ++r) acc[t][r] = 0.f;

  float mrun = -1e30f, lsum = 0.f;

  // staging registers (tile t+1 in flight)
  uint4 vreg[8];
  uint4 kreg;
  const int vpart = tid & 3;          // 4 x 8-key pieces per c-row
  const int kd = tid >> 2, kpart = tid & 3;

  auto LOADS = [&](int n0k) {
#pragma unroll
    for (int r = 0; r < 8; ++r) {
      int c = r * 32 + (tid >> 2);
      vreg[r] = *(const uint4*)(vb + (size_t)c * 4096 + n0k + vpart * 8);
    }
    kreg = *(const uint4*)(kb + (size_t)kd * 4096 + n0k + kpart * 8);
  };

  LOADS(0);

  for (int t = 0; t < 128; ++t) {
    __syncthreads();
    // commit staged regs -> LDS
#pragma unroll
    for (int r = 0; r < 8; ++r) {
      int c = r * 32 + (tid >> 2);
      *(uint4*)&vS[c * 40 + vpart * 8] = vreg[r];
    }
    {
      const ushort* ksrc = (const ushort*)&kreg;
#pragma unroll
      for (int e = 0; e < 8; ++e)
        kT[(kpart * 8 + e) * 40 + kd] = ksrc[e];   // transpose k -> kT[n][d]
    }
    __syncthreads();
    if (t < 127) LOADS((t + 1) * 32);              // prefetch hides under compute

    // --- QK^T (swapped): S^T[key][m], scores already in log2 domain ---
    bf16x8 ka0 = *(const bf16x8*)&kT[l31 * 40 + 8 * hi];        // d = 8hi..8hi+7
    bf16x8 ka1 = *(const bf16x8*)&kT[l31 * 40 + 16 + 8 * hi];   // d = 16+8hi..
    f32x16 s;
#pragma unroll
    for (int r = 0; r < 16; ++r) s[r] = 0.f;
    s = __builtin_amdgcn_mfma_f32_32x32x16_bf16(ka0, qf0, s, 0, 0, 0);
    s = __builtin_amdgcn_mfma_f32_32x32x16_bf16(ka1, qf1, s, 0, 0, 0);

    // --- online softmax (per-lane: one m, 16 of 32 keys) ---
    float pm = s[0];
#pragma unroll
    for (int r = 1; r < 16; ++r) pm = fmaxf(pm, s[r]);
    pm = fmaxf(pm, __shfl_xor(pm, 32));            // combine the two key-halves

    if (!__all(pm <= mrun + 8.0f)) {               // defer-max (T13), log2 domain
      float mnew = fmaxf(mrun, pm);
      float a = EXP2(mrun - mnew);
      mrun = mnew;
      lsum *= a;
#pragma unroll
      for (int t8 = 0; t8 < 8; ++t8)
#pragma unroll
        for (int r = 0; r < 16; ++r) acc[t8][r] *= a;
    }

    float p[16];
    float ps = 0.f;
#pragma unroll
    for (int r = 0; r < 16; ++r) { p[r] = EXP2(s[r] - mrun); ps += p[r]; }
    ps += __shfl_xor(ps, 32);
    lsum += ps;

    // --- pack P -> bf16 PV B-frags (T12: cvt_pk + permlane32_swap) ---
    uint pw[8];
#pragma unroll
    for (int j = 0; j < 8; ++j) pw[j] = cvtpk_bf16(p[2 * j], p[2 * j + 1]);
    plswap(pw[0], pw[2]); plswap(pw[1], pw[3]);
    plswap(pw[4], pw[6]); plswap(pw[5], pw[7]);
    union { uint w[4]; bf16x8 v; } pb0u, pb1u;
    pb0u.w[0] = pw[0]; pb0u.w[1] = pw[1]; pb0u.w[2] = pw[2]; pb0u.w[3] = pw[3];
    pb1u.w[0] = pw[4]; pb1u.w[1] = pw[5]; pb1u.w[2] = pw[6]; pb1u.w[3] = pw[7];
    bf16x8 pb0 = pb0u.v, pb1 = pb1u.v;

    // --- PV: O^T[c][m] += V[c][keys] * P^T[keys][m] ---
#pragma unroll
    for (int t8 = 0; t8 < 8; ++t8) {
      bf16x8 va0 = *(const bf16x8*)&vS[(t8 * 32 + l31) * 40 + 8 * hi];
      bf16x8 va1 = *(const bf16x8*)&vS[(t8 * 32 + l31) * 40 + 16 + 8 * hi];
      acc[t8] = __builtin_amdgcn_mfma_f32_32x32x16_bf16(va0, pb0, acc[t8], 0, 0, 0);
      acc[t8] = __builtin_amdgcn_mfma_f32_32x32x16_bf16(va1, pb1, acc[t8], 0, 0, 0);
    }
  }

  // --- epilogue: normalize, gamma*out + x ---
  float inv = 1.0f / lsum;
  float g = gamma[0];
  const float* xc = x + (size_t)b * 256 * 4096 + m;
  float* oc = out + (size_t)b * 256 * 4096 + m;
#pragma unroll
  for (int t8 = 0; t8 < 8; ++t8) {
#pragma unroll
    for (int r = 0; r < 16; ++r) {
      int c = t8 * 32 + (r & 3) + 8 * (r >> 2) + 4 * hi;
      oc[(size_t)c * 4096] = g * (acc[t8][r] * inv) + xc[(size_t)c * 4096];
    }
  }
}

extern "C" void kernel_launch(void* const* d_in, const int* in_sizes, int n_in,
                              void* d_out, int out_size, void* d_ws, size_t ws_size,
                              hipStream_t stream) {
  const float* x  = (const float*)d_in[0];
  const float* Wq = (const float*)d_in[1];
  const float* bq = (const float*)d_in[2];
  const float* Wk = (const float*)d_in[3];
  const float* bk = (const float*)d_in[4];
  const float* Wv = (const float*)d_in[5];
  const float* bv = (const float*)d_in[6];
  const float* gm = (const float*)d_in[7];
  float* out = (float*)d_out;

  // ws: qs [8][32][4096] bf16 | k [8][32][4096] bf16 | v [8][256][4096] bf16 (20 MB)
  ushort* qs = (ushort*)d_ws;
  ushort* ko = qs + (size_t)8 * 32 * 4096;
  ushort* vo = ko + (size_t)8 * 32 * 4096;

  proj_qkv<<<dim3(16, 8, 5), 256, 0, stream>>>(x, Wq, bq, Wk, bk, Wv, bv, qs, ko, vo);
  attn_fused<<<dim3(512), 128, 0, stream>>>(qs, ko, vo, x, gm, out);
}

// Round 2
// 234.156 us; speedup vs baseline: 1.7106x; 1.7106x over previous
//
#include <hip/hip_runtime.h>
#include <cstdint>

typedef __bf16 bf16x8 __attribute__((ext_vector_type(8)));
typedef float f32x16 __attribute__((ext_vector_type(16)));

#define LOG2E 1.44269504088896340736f

static __device__ __forceinline__ ushort f2bf(float f) {
  uint u = __builtin_bit_cast(uint, f);
  u = u + 0x7FFFu + ((u >> 16) & 1u);   // RNE
  return (ushort)(u >> 16);
}

static __device__ __forceinline__ uint cvtpk_bf16(float lo, float hi) {
  uint r;
  asm("v_cvt_pk_bf16_f32 %0, %1, %2" : "=v"(r) : "v"(lo), "v"(hi));
  return r;
}

static __device__ __forceinline__ void plswap(uint& a, uint& b) {
  asm("v_permlane32_swap_b32 %0, %1" : "+v"(a), "+v"(b));
}

#if __has_builtin(__builtin_amdgcn_exp2f)
#define EXP2(x) __builtin_amdgcn_exp2f(x)
#else
#define EXP2(x) exp2f(x)
#endif

// ---------------------------------------------------------------------------
// Workspace layouts (all bf16 as ushort):
//   qs : [b][32 d][4096 m]                      (2 MB)  column-gather at attn start
//   kz : [b][128 T][frag j(2)][lane(64)][i(8)]  (2 MB)  K-tile fragment-major
//        elem(b,T,kk,d) = b*131072 + T*1024 + (d>>4)*512 + ((d>>3)&1)*256 + kk*8 + (d&7)
//   vz : [b][128 T][frag j(16)][lane(64)][i(8)] (16 MB) V-tile fragment-major
//        elem(b,T,c,kk) = b*1048576 + T*8192 + ((c>>5)*2+(kk>>4))*512
//                         + ((kk>>3)&1)*256 + (c&31)*8 + (kk&7)
// A-frag convention (verified R1): lane holds A[row=l31][k=8*hi+i].
// ---------------------------------------------------------------------------

__global__ __launch_bounds__(256, 2) void proj_qkv(
    const float* __restrict__ x,
    const float* __restrict__ Wq, const float* __restrict__ bq,
    const float* __restrict__ Wk, const float* __restrict__ bk,
    const float* __restrict__ Wv, const float* __restrict__ bv,
    ushort* __restrict__ qo, ushort* __restrict__ ko, ushort* __restrict__ vo)
{
  __shared__ float xs[32][256];   // [c][n]
  __shared__ float wt[32][64];    // [c][d] (transposed W chunk)

  const int tid = threadIdx.x;
  const int nt = blockIdx.x, b = blockIdx.y, dt = blockIdx.z;
  const int n0 = nt * 256;
  const int nthr = tid & 31;      // 32 n-groups (two 4-wide slots: 4*nthr, 4*nthr+128)
  const int dthr = tid >> 5;      // 8 d-groups of 8 rows

  float acc[8][8];
#pragma unroll
  for (int i = 0; i < 8; ++i)
#pragma unroll
    for (int j = 0; j < 8; ++j) acc[i][j] = 0.f;

  const float* xb = x + (size_t)b * 256 * 4096;

  for (int kc = 0; kc < 8; ++kc) {
    const int c0 = kc * 32;
    __syncthreads();
#pragma unroll
    for (int r = 0; r < 8; ++r) {
      int id = r * 256 + tid;
      int c = id >> 6, pos = (id & 63) * 4;
      float4 v = *(const float4*)(xb + (size_t)(c0 + c) * 4096 + n0 + pos);
      *(float4*)&xs[c][pos] = v;
    }
#pragma unroll
    for (int r = 0; r < 2; ++r) {
      int id = r * 256 + tid;
      int d = id >> 3, c4 = (id & 7) * 4;
      int grow = dt * 64 + d;
      const float* wrow;
      float scale = 1.f;
      if (dt == 0) {
        if (grow < 32) { wrow = Wq + (size_t)grow * 256; scale = LOG2E; }
        else           { wrow = Wk + (size_t)(grow - 32) * 256; }
      } else {
        wrow = Wv + (size_t)(grow - 64) * 256;
      }
      float4 v = *(const float4*)(wrow + c0 + c4);
      wt[c4 + 0][d] = v.x * scale;
      wt[c4 + 1][d] = v.y * scale;
      wt[c4 + 2][d] = v.z * scale;
      wt[c4 + 3][d] = v.w * scale;
    }
    __syncthreads();

#pragma unroll
    for (int cc = 0; cc < 32; ++cc) {
      float4 xv0 = *(const float4*)&xs[cc][nthr * 4];
      float4 xv1 = *(const float4*)&xs[cc][nthr * 4 + 128];
      float4 wv0 = *(const float4*)&wt[cc][dthr * 8];
      float4 wv1 = *(const float4*)&wt[cc][dthr * 8 + 4];
      float wr[8] = {wv0.x, wv0.y, wv0.z, wv0.w, wv1.x, wv1.y, wv1.z, wv1.w};
      float xr[8] = {xv0.x, xv0.y, xv0.z, xv0.w, xv1.x, xv1.y, xv1.z, xv1.w};
#pragma unroll
      for (int dd = 0; dd < 8; ++dd)
#pragma unroll
        for (int nn = 0; nn < 8; ++nn)
          acc[dd][nn] = fmaf(wr[dd], xr[nn], acc[dd][nn]);
    }
  }

  // ---- epilogue ----
  if (dt == 0 && dthr < 4) {
    // q rows: plain [d][m] bf16, pre-scaled by log2e (weights already scaled)
#pragma unroll
    for (int dd = 0; dd < 8; ++dd) {
      int grow = dthr * 8 + dd;
      ushort* dst = qo + ((size_t)b * 32 + grow) * 4096;
      float bias = bq[grow] * LOG2E;
      ushort4 w0, w1;
      w0.x = f2bf(acc[dd][0] + bias); w0.y = f2bf(acc[dd][1] + bias);
      w0.z = f2bf(acc[dd][2] + bias); w0.w = f2bf(acc[dd][3] + bias);
      w1.x = f2bf(acc[dd][4] + bias); w1.y = f2bf(acc[dd][5] + bias);
      w1.z = f2bf(acc[dd][6] + bias); w1.w = f2bf(acc[dd][7] + bias);
      *(ushort4*)(dst + n0 + nthr * 4) = w0;
      *(ushort4*)(dst + n0 + nthr * 4 + 128) = w1;
    }
  } else if (dt == 0) {
    // k rows -> kz fragment-major. dk = (dthr-4)*8 + dd; per thread j,hi const.
    const int dkbase = (dthr - 4) * 8;
    const int j = dkbase >> 4;
    const int khi = (dkbase >> 3) & 1;
    float bias[8];
#pragma unroll
    for (int dd = 0; dd < 8; ++dd) bias[dd] = bk[dkbase + dd];
    const size_t kzb = (size_t)b * 131072;
#pragma unroll
    for (int nn = 0; nn < 8; ++nn) {
      int n = n0 + nthr * 4 + (nn & 3) + (nn >> 2) * 128;
      int kk = n & 31, T = n >> 5;
      size_t base = kzb + (size_t)T * 1024 + j * 512 + khi * 256 + kk * 8;
      ushort4 a, bb;
      a.x = f2bf(acc[0][nn] + bias[0]); a.y = f2bf(acc[1][nn] + bias[1]);
      a.z = f2bf(acc[2][nn] + bias[2]); a.w = f2bf(acc[3][nn] + bias[3]);
      bb.x = f2bf(acc[4][nn] + bias[4]); bb.y = f2bf(acc[5][nn] + bias[5]);
      bb.z = f2bf(acc[6][nn] + bias[6]); bb.w = f2bf(acc[7][nn] + bias[7]);
      *(ushort4*)(ko + base) = a;
      *(ushort4*)(ko + base + 4) = bb;
    }
  } else {
    // v rows -> vz fragment-major
    const int cbase = (dt - 1) * 64 + dthr * 8;
    const int kk4 = (nthr * 4) & 31;       // key-in-tile for nn 0..3 (same for 4..7)
    const int T0 = (n0 + nthr * 4) >> 5;
    const int vhi = (kk4 >> 3) & 1;
    const int i4 = kk4 & 7;                // 0 or 4
    const size_t vzb = (size_t)b * 1048576;
#pragma unroll
    for (int dd = 0; dd < 8; ++dd) {
      int c = cbase + dd;
      float bias = bv[c];
      int jj = (c >> 5) * 2 + (kk4 >> 4);
      int l = c & 31;
      size_t off0 = vzb + (size_t)T0 * 8192 + (size_t)jj * 512 + vhi * 256 + l * 8 + i4;
      ushort4 w0, w1;
      w0.x = f2bf(acc[dd][0] + bias); w0.y = f2bf(acc[dd][1] + bias);
      w0.z = f2bf(acc[dd][2] + bias); w0.w = f2bf(acc[dd][3] + bias);
      w1.x = f2bf(acc[dd][4] + bias); w1.y = f2bf(acc[dd][5] + bias);
      w1.z = f2bf(acc[dd][6] + bias); w1.w = f2bf(acc[dd][7] + bias);
      *(ushort4*)(vo + off0) = w0;
      *(ushort4*)(vo + off0 + 4 * 8192) = w1;   // n+128: same kk, T0+4
    }
  }
}

// ---------------------------------------------------------------------------
// Kernel 2: fused flash attention + residual. Key-split x2, no inner-loop LDS.
// Block = 128 thr (2 waves). Both waves own the SAME 32 query columns;
// wave w processes key tiles [w*64, w*64+64). All K/V fragment loads are
// fully-coalesced 1 KB streams from the fragment-major layouts (L2-resident,
// one batch per XCD via swizzle). End: merge partials (m,l,acc) via LDS.
// ---------------------------------------------------------------------------
__global__ __launch_bounds__(128, 2) void attn_fused(
    const ushort* __restrict__ qs, const ushort* __restrict__ kz,
    const ushort* __restrict__ vz, const float* __restrict__ x,
    const float* __restrict__ gamma, float* __restrict__ out)
{
  __shared__ float xch[2][4][16][64];   // 32 KB acc exchange
  __shared__ float sml[2][2][64];       // (m, l) exchange

  const int wg = blockIdx.x;                      // 0..1023
  const int swz = (wg & 7) * 128 + (wg >> 3);     // one batch per XCD
  const int b = swz >> 7, mt = swz & 127;
  const int tid = threadIdx.x;
  const int w = tid >> 6, lane = tid & 63;
  const int l31 = lane & 31, hi = lane >> 5;
  const int m = mt * 32 + l31;

  // resident Q B-frags: qf[j] holds q[j*16 + 8*hi + i][m]
  const ushort* qcol = qs + (size_t)b * 131072 + m;
  bf16x8 qf0, qf1;
  {
    union { ushort s[8]; bf16x8 v; } u0, u1;
#pragma unroll
    for (int i = 0; i < 8; ++i) {
      u0.s[i] = qcol[(size_t)(8 * hi + i) * 4096];
      u1.s[i] = qcol[(size_t)(16 + 8 * hi + i) * 4096];
    }
    qf0 = u0.v; qf1 = u1.v;
  }

  const ushort* kb = kz + (size_t)b * 131072 + (size_t)w * 64 * 1024;
  const ushort* vb = vz + (size_t)b * 1048576 + (size_t)w * 64 * 8192;

  f32x16 acc[8];
#pragma unroll
  for (int t8 = 0; t8 < 8; ++t8)
#pragma unroll
    for (int r = 0; r < 16; ++r) acc[t8][r] = 0.f;

  float mrun = -1e30f, lsum = 0.f;

  for (int t = 0; t < 64; ++t) {
    const ushort* kt = kb + t * 1024;
    bf16x8 ka0 = *(const bf16x8*)(kt + lane * 8);
    bf16x8 ka1 = *(const bf16x8*)(kt + 512 + lane * 8);

    f32x16 s;
#pragma unroll
    for (int r = 0; r < 16; ++r) s[r] = 0.f;
    s = __builtin_amdgcn_mfma_f32_32x32x16_bf16(ka0, qf0, s, 0, 0, 0);
    s = __builtin_amdgcn_mfma_f32_32x32x16_bf16(ka1, qf1, s, 0, 0, 0);

    // online softmax (log2 domain; lane covers 16 of 32 keys, one m)
    float pm = s[0];
#pragma unroll
    for (int r = 1; r < 16; ++r) pm = fmaxf(pm, s[r]);
    pm = fmaxf(pm, __shfl_xor(pm, 32));

    if (!__all(pm <= mrun + 8.0f)) {              // defer-max (T13)
      float mnew = fmaxf(mrun, pm);
      float a = EXP2(mrun - mnew);
      mrun = mnew;
      lsum *= a;
#pragma unroll
      for (int t8 = 0; t8 < 8; ++t8)
#pragma unroll
        for (int r = 0; r < 16; ++r) acc[t8][r] *= a;
    }

    float p[16];
    float ps = 0.f;
#pragma unroll
    for (int r = 0; r < 16; ++r) { p[r] = EXP2(s[r] - mrun); ps += p[r]; }
    ps += __shfl_xor(ps, 32);
    lsum += ps;

    // pack P -> bf16 PV B-frags (T12)
    uint pw[8];
#pragma unroll
    for (int j = 0; j < 8; ++j) pw[j] = cvtpk_bf16(p[2 * j], p[2 * j + 1]);
    plswap(pw[0], pw[2]); plswap(pw[1], pw[3]);
    plswap(pw[4], pw[6]); plswap(pw[5], pw[7]);
    union { uint u[4]; bf16x8 v; } pb0u, pb1u;
    pb0u.u[0] = pw[0]; pb0u.u[1] = pw[1]; pb0u.u[2] = pw[2]; pb0u.u[3] = pw[3];
    pb1u.u[0] = pw[4]; pb1u.u[1] = pw[5]; pb1u.u[2] = pw[6]; pb1u.u[3] = pw[7];
    bf16x8 pb0 = pb0u.v, pb1 = pb1u.v;

    // PV: O^T[c][m] += V[c][keys] * P^T[keys][m]   (streamed frags, L2-hit)
    const ushort* vt = vb + (size_t)t * 8192;
#pragma unroll
    for (int t8 = 0; t8 < 8; ++t8) {
      bf16x8 va0 = *(const bf16x8*)(vt + (t8 * 2 + 0) * 512 + lane * 8);
      bf16x8 va1 = *(const bf16x8*)(vt + (t8 * 2 + 1) * 512 + lane * 8);
      acc[t8] = __builtin_amdgcn_mfma_f32_32x32x16_bf16(va0, pb0, acc[t8], 0, 0, 0);
      acc[t8] = __builtin_amdgcn_mfma_f32_32x32x16_bf16(va1, pb1, acc[t8], 0, 0, 0);
    }
  }

  // ---- merge the two key-split partials ----
  sml[w][0][lane] = mrun; sml[w][1][lane] = lsum;
  __syncthreads();
  const float mo = sml[1 - w][0][lane], lo = sml[1 - w][1][lane];
  const float mstar = fmaxf(mrun, mo);
  const float aw = EXP2(mrun - mstar);
  const float ao = EXP2(mo - mstar);
  const float ltot = lsum * aw + lo * ao;
#pragma unroll
  for (int t8 = 0; t8 < 8; ++t8)
#pragma unroll
    for (int r = 0; r < 16; ++r) acc[t8][r] *= aw;

  // ship the half we don't own (wave0 owns t8 0..3, wave1 owns 4..7)
  const int ship0 = w ? 0 : 4;
#pragma unroll
  for (int q = 0; q < 4; ++q)
#pragma unroll
    for (int r = 0; r < 16; ++r)
      xch[w][q][r][lane] = acc[ship0 + q][r];
  __syncthreads();

  const int own0 = w ? 4 : 0;
  const float inv = 1.0f / ltot;
  const float g = gamma[0];
  const float* xc = x + (size_t)b * 256 * 4096 + m;
  float* oc = out + (size_t)b * 256 * 4096 + m;
#pragma unroll
  for (int q = 0; q < 4; ++q) {
    const int t8 = own0 + q;
#pragma unroll
    for (int r = 0; r < 16; ++r) {
      float val = acc[t8][r] + xch[1 - w][q][r][lane];
      int c = t8 * 32 + (r & 3) + 8 * (r >> 2) + 4 * hi;
      oc[(size_t)c * 4096] = g * (val * inv) + xc[(size_t)c * 4096];
    }
  }
}

extern "C" void kernel_launch(void* const* d_in, const int* in_sizes, int n_in,
                              void* d_out, int out_size, void* d_ws, size_t ws_size,
                              hipStream_t stream) {
  const float* x  = (const float*)d_in[0];
  const float* Wq = (const float*)d_in[1];
  const float* bq = (const float*)d_in[2];
  const float* Wk = (const float*)d_in[3];
  const float* bk = (const float*)d_in[4];
  const float* Wv = (const float*)d_in[5];
  const float* bv = (const float*)d_in[6];
  const float* gm = (const float*)d_in[7];
  float* out = (float*)d_out;

  // ws: qs 2MB | kz 2MB | vz 16MB  (bf16 as ushort)
  ushort* qs = (ushort*)d_ws;
  ushort* kzp = qs + (size_t)8 * 131072;
  ushort* vzp = kzp + (size_t)8 * 131072;

  proj_qkv<<<dim3(16, 8, 5), 256, 0, stream>>>(x, Wq, bq, Wk, bk, Wv, bv, qs, kzp, vzp);
  attn_fused<<<dim3(1024), 128, 0, stream>>>(qs, kzp, vzp, x, gm, out);
}

// Round 3
// 212.201 us; speedup vs baseline: 1.8875x; 1.1035x over previous
//
#include <hip/hip_runtime.h>
#include <cstdint>

typedef __bf16 bf16x8 __attribute__((ext_vector_type(8)));
typedef float f32x16 __attribute__((ext_vector_type(16)));

#define LOG2E 1.44269504088896340736f

static __device__ __forceinline__ ushort f2bf(float f) {
  uint u = __builtin_bit_cast(uint, f);
  u = u + 0x7FFFu + ((u >> 16) & 1u);   // RNE
  return (ushort)(u >> 16);
}

static __device__ __forceinline__ uint cvtpk_bf16(float lo, float hi) {
  uint r;
  asm("v_cvt_pk_bf16_f32 %0, %1, %2" : "=v"(r) : "v"(lo), "v"(hi));
  return r;
}

static __device__ __forceinline__ void plswap(uint& a, uint& b) {
  asm("v_permlane32_swap_b32 %0, %1" : "+v"(a), "+v"(b));
}

#if __has_builtin(__builtin_amdgcn_exp2f)
#define EXP2(x) __builtin_amdgcn_exp2f(x)
#else
#define EXP2(x) exp2f(x)
#endif

// ---------------------------------------------------------------------------
// Workspace layouts (all bf16 as ushort):
//   qs : [b][32 d][4096 m]                      (2 MB)
//   kz : [b][128 T][frag j(2)][lane(64)][i(8)]  (2 MB)  K-tile fragment-major
//   vz : [b][128 T][frag j(16)][lane(64)][i(8)] (16 MB) V-tile fragment-major
// A-frag convention (verified R1): lane holds A[row=l31][k=8*hi+i].
// ---------------------------------------------------------------------------

__global__ __launch_bounds__(256, 2) void proj_qkv(
    const float* __restrict__ x,
    const float* __restrict__ Wq, const float* __restrict__ bq,
    const float* __restrict__ Wk, const float* __restrict__ bk,
    const float* __restrict__ Wv, const float* __restrict__ bv,
    ushort* __restrict__ qo, ushort* __restrict__ ko, ushort* __restrict__ vo)
{
  __shared__ float xs[32][256];   // [c][n]
  __shared__ float wt[32][64];    // [c][d] (transposed W chunk)

  const int tid = threadIdx.x;
  const int nt = blockIdx.x, b = blockIdx.y, dt = blockIdx.z;
  const int n0 = nt * 256;
  const int nthr = tid & 31;
  const int dthr = tid >> 5;

  float acc[8][8];
#pragma unroll
  for (int i = 0; i < 8; ++i)
#pragma unroll
    for (int j = 0; j < 8; ++j) acc[i][j] = 0.f;

  const float* xb = x + (size_t)b * 256 * 4096;

  for (int kc = 0; kc < 8; ++kc) {
    const int c0 = kc * 32;
    __syncthreads();
#pragma unroll
    for (int r = 0; r < 8; ++r) {
      int id = r * 256 + tid;
      int c = id >> 6, pos = (id & 63) * 4;
      float4 v = *(const float4*)(xb + (size_t)(c0 + c) * 4096 + n0 + pos);
      *(float4*)&xs[c][pos] = v;
    }
#pragma unroll
    for (int r = 0; r < 2; ++r) {
      int id = r * 256 + tid;
      int d = id >> 3, c4 = (id & 7) * 4;
      int grow = dt * 64 + d;
      const float* wrow;
      float scale = 1.f;
      if (dt == 0) {
        if (grow < 32) { wrow = Wq + (size_t)grow * 256; scale = LOG2E; }
        else           { wrow = Wk + (size_t)(grow - 32) * 256; }
      } else {
        wrow = Wv + (size_t)(grow - 64) * 256;
      }
      float4 v = *(const float4*)(wrow + c0 + c4);
      wt[c4 + 0][d] = v.x * scale;
      wt[c4 + 1][d] = v.y * scale;
      wt[c4 + 2][d] = v.z * scale;
      wt[c4 + 3][d] = v.w * scale;
    }
    __syncthreads();

#pragma unroll
    for (int cc = 0; cc < 32; ++cc) {
      float4 xv0 = *(const float4*)&xs[cc][nthr * 4];
      float4 xv1 = *(const float4*)&xs[cc][nthr * 4 + 128];
      float4 wv0 = *(const float4*)&wt[cc][dthr * 8];
      float4 wv1 = *(const float4*)&wt[cc][dthr * 8 + 4];
      float wr[8] = {wv0.x, wv0.y, wv0.z, wv0.w, wv1.x, wv1.y, wv1.z, wv1.w};
      float xr[8] = {xv0.x, xv0.y, xv0.z, xv0.w, xv1.x, xv1.y, xv1.z, xv1.w};
#pragma unroll
      for (int dd = 0; dd < 8; ++dd)
#pragma unroll
        for (int nn = 0; nn < 8; ++nn)
          acc[dd][nn] = fmaf(wr[dd], xr[nn], acc[dd][nn]);
    }
  }

  // ---- epilogue ----
  if (dt == 0 && dthr < 4) {
#pragma unroll
    for (int dd = 0; dd < 8; ++dd) {
      int grow = dthr * 8 + dd;
      ushort* dst = qo + ((size_t)b * 32 + grow) * 4096;
      float bias = bq[grow] * LOG2E;
      ushort4 w0, w1;
      w0.x = f2bf(acc[dd][0] + bias); w0.y = f2bf(acc[dd][1] + bias);
      w0.z = f2bf(acc[dd][2] + bias); w0.w = f2bf(acc[dd][3] + bias);
      w1.x = f2bf(acc[dd][4] + bias); w1.y = f2bf(acc[dd][5] + bias);
      w1.z = f2bf(acc[dd][6] + bias); w1.w = f2bf(acc[dd][7] + bias);
      *(ushort4*)(dst + n0 + nthr * 4) = w0;
      *(ushort4*)(dst + n0 + nthr * 4 + 128) = w1;
    }
  } else if (dt == 0) {
    const int dkbase = (dthr - 4) * 8;
    const int j = dkbase >> 4;
    const int khi = (dkbase >> 3) & 1;
    float bias[8];
#pragma unroll
    for (int dd = 0; dd < 8; ++dd) bias[dd] = bk[dkbase + dd];
    const size_t kzb = (size_t)b * 131072;
#pragma unroll
    for (int nn = 0; nn < 8; ++nn) {
      int n = n0 + nthr * 4 + (nn & 3) + (nn >> 2) * 128;
      int kk = n & 31, T = n >> 5;
      size_t base = kzb + (size_t)T * 1024 + j * 512 + khi * 256 + kk * 8;
      ushort4 a, bb;
      a.x = f2bf(acc[0][nn] + bias[0]); a.y = f2bf(acc[1][nn] + bias[1]);
      a.z = f2bf(acc[2][nn] + bias[2]); a.w = f2bf(acc[3][nn] + bias[3]);
      bb.x = f2bf(acc[4][nn] + bias[4]); bb.y = f2bf(acc[5][nn] + bias[5]);
      bb.z = f2bf(acc[6][nn] + bias[6]); bb.w = f2bf(acc[7][nn] + bias[7]);
      *(ushort4*)(ko + base) = a;
      *(ushort4*)(ko + base + 4) = bb;
    }
  } else {
    const int cbase = (dt - 1) * 64 + dthr * 8;
    const int kk4 = (nthr * 4) & 31;
    const int T0 = (n0 + nthr * 4) >> 5;
    const int vhi = (kk4 >> 3) & 1;
    const int i4 = kk4 & 7;
    const size_t vzb = (size_t)b * 1048576;
#pragma unroll
    for (int dd = 0; dd < 8; ++dd) {
      int c = cbase + dd;
      float bias = bv[c];
      int jj = (c >> 5) * 2 + (kk4 >> 4);
      int l = c & 31;
      size_t off0 = vzb + (size_t)T0 * 8192 + (size_t)jj * 512 + vhi * 256 + l * 8 + i4;
      ushort4 w0, w1;
      w0.x = f2bf(acc[dd][0] + bias); w0.y = f2bf(acc[dd][1] + bias);
      w0.z = f2bf(acc[dd][2] + bias); w0.w = f2bf(acc[dd][3] + bias);
      w1.x = f2bf(acc[dd][4] + bias); w1.y = f2bf(acc[dd][5] + bias);
      w1.z = f2bf(acc[dd][6] + bias); w1.w = f2bf(acc[dd][7] + bias);
      *(ushort4*)(vo + off0) = w0;
      *(ushort4*)(vo + off0 + 4 * 8192) = w1;
    }
  }
}

// ---------------------------------------------------------------------------
// Kernel 2: fused flash attention + residual. Key-split x2, no inner-loop LDS.
// NOTE (rule #20): the merge epilogue uses wave-uniform if/else with
// COMPILE-TIME acc indices only — a runtime `acc[ship0+q]` index here
// previously forced the whole accumulator into scratch (VGPR=104,
// +162 MB HBM writes, 2x slowdown).
// ---------------------------------------------------------------------------
__global__ __launch_bounds__(128, 2) void attn_fused(
    const ushort* __restrict__ qs, const ushort* __restrict__ kz,
    const ushort* __restrict__ vz, const float* __restrict__ x,
    const float* __restrict__ gamma, float* __restrict__ out)
{
  __shared__ float xch[2][4][16][64];   // 32 KB acc exchange
  __shared__ float sml[2][2][64];       // (m, l) exchange

  const int wg = blockIdx.x;                      // 0..1023
  const int swz = (wg & 7) * 128 + (wg >> 3);     // one batch per XCD
  const int b = swz >> 7, mt = swz & 127;
  const int tid = threadIdx.x;
  const int w = tid >> 6, lane = tid & 63;
  const int l31 = lane & 31, hi = lane >> 5;
  const int m = mt * 32 + l31;

  // resident Q B-frags: qf[j] holds q[j*16 + 8*hi + i][m]
  const ushort* qcol = qs + (size_t)b * 131072 + m;
  bf16x8 qf0, qf1;
  {
    union { ushort s[8]; bf16x8 v; } u0, u1;
#pragma unroll
    for (int i = 0; i < 8; ++i) {
      u0.s[i] = qcol[(size_t)(8 * hi + i) * 4096];
      u1.s[i] = qcol[(size_t)(16 + 8 * hi + i) * 4096];
    }
    qf0 = u0.v; qf1 = u1.v;
  }

  const ushort* kb = kz + (size_t)b * 131072 + (size_t)w * 64 * 1024;
  const ushort* vb = vz + (size_t)b * 1048576 + (size_t)w * 64 * 8192;

  f32x16 acc[8];
#pragma unroll
  for (int t8 = 0; t8 < 8; ++t8)
#pragma unroll
    for (int r = 0; r < 16; ++r) acc[t8][r] = 0.f;

  float mrun = -1e30f, lsum = 0.f;

  for (int t = 0; t < 64; ++t) {
    const ushort* kt = kb + t * 1024;
    bf16x8 ka0 = *(const bf16x8*)(kt + lane * 8);
    bf16x8 ka1 = *(const bf16x8*)(kt + 512 + lane * 8);

    f32x16 s;
#pragma unroll
    for (int r = 0; r < 16; ++r) s[r] = 0.f;
    s = __builtin_amdgcn_mfma_f32_32x32x16_bf16(ka0, qf0, s, 0, 0, 0);
    s = __builtin_amdgcn_mfma_f32_32x32x16_bf16(ka1, qf1, s, 0, 0, 0);

    // online softmax (log2 domain; lane covers 16 of 32 keys, one m)
    float pm = s[0];
#pragma unroll
    for (int r = 1; r < 16; ++r) pm = fmaxf(pm, s[r]);
    pm = fmaxf(pm, __shfl_xor(pm, 32));

    if (!__all(pm <= mrun + 8.0f)) {              // defer-max (T13)
      float mnew = fmaxf(mrun, pm);
      float a = EXP2(mrun - mnew);
      mrun = mnew;
      lsum *= a;
#pragma unroll
      for (int t8 = 0; t8 < 8; ++t8)
#pragma unroll
        for (int r = 0; r < 16; ++r) acc[t8][r] *= a;
    }

    float p[16];
    float ps = 0.f;
#pragma unroll
    for (int r = 0; r < 16; ++r) { p[r] = EXP2(s[r] - mrun); ps += p[r]; }
    ps += __shfl_xor(ps, 32);
    lsum += ps;

    // pack P -> bf16 PV B-frags (T12)
    uint pw[8];
#pragma unroll
    for (int j = 0; j < 8; ++j) pw[j] = cvtpk_bf16(p[2 * j], p[2 * j + 1]);
    plswap(pw[0], pw[2]); plswap(pw[1], pw[3]);
    plswap(pw[4], pw[6]); plswap(pw[5], pw[7]);
    union { uint u[4]; bf16x8 v; } pb0u, pb1u;
    pb0u.u[0] = pw[0]; pb0u.u[1] = pw[1]; pb0u.u[2] = pw[2]; pb0u.u[3] = pw[3];
    pb1u.u[0] = pw[4]; pb1u.u[1] = pw[5]; pb1u.u[2] = pw[6]; pb1u.u[3] = pw[7];
    bf16x8 pb0 = pb0u.v, pb1 = pb1u.v;

    // PV: O^T[c][m] += V[c][keys] * P^T[keys][m]   (streamed frags, L2-hit)
    const ushort* vt = vb + (size_t)t * 8192;
#pragma unroll
    for (int t8 = 0; t8 < 8; ++t8) {
      bf16x8 va0 = *(const bf16x8*)(vt + (t8 * 2 + 0) * 512 + lane * 8);
      bf16x8 va1 = *(const bf16x8*)(vt + (t8 * 2 + 1) * 512 + lane * 8);
      acc[t8] = __builtin_amdgcn_mfma_f32_32x32x16_bf16(va0, pb0, acc[t8], 0, 0, 0);
      acc[t8] = __builtin_amdgcn_mfma_f32_32x32x16_bf16(va1, pb1, acc[t8], 0, 0, 0);
    }
  }

  // ---- merge the two key-split partials (all acc indices compile-time) ----
  sml[w][0][lane] = mrun; sml[w][1][lane] = lsum;
  __syncthreads();
  const float mo = sml[1 - w][0][lane], lo = sml[1 - w][1][lane];
  const float mstar = fmaxf(mrun, mo);
  const float aw = EXP2(mrun - mstar);
  const float ao = EXP2(mo - mstar);
  const float ltot = lsum * aw + lo * ao;
#pragma unroll
  for (int t8 = 0; t8 < 8; ++t8)
#pragma unroll
    for (int r = 0; r < 16; ++r) acc[t8][r] *= aw;

  // ship the half we don't own (wave0 owns t8 0..3, wave1 owns 4..7)
  if (w == 0) {
#pragma unroll
    for (int q = 0; q < 4; ++q)
#pragma unroll
      for (int r = 0; r < 16; ++r)
        xch[0][q][r][lane] = acc[4 + q][r];
  } else {
#pragma unroll
    for (int q = 0; q < 4; ++q)
#pragma unroll
      for (int r = 0; r < 16; ++r)
        xch[1][q][r][lane] = acc[q][r];
  }
  __syncthreads();

  const float inv = 1.0f / ltot;
  const float g = gamma[0];
  const float* xc = x + (size_t)b * 256 * 4096 + m;
  float* oc = out + (size_t)b * 256 * 4096 + m;
  if (w == 0) {
#pragma unroll
    for (int q = 0; q < 4; ++q) {
#pragma unroll
      for (int r = 0; r < 16; ++r) {
        float val = acc[q][r] + xch[1][q][r][lane];
        int c = q * 32 + (r & 3) + 8 * (r >> 2) + 4 * hi;
        oc[(size_t)c * 4096] = g * (val * inv) + xc[(size_t)c * 4096];
      }
    }
  } else {
#pragma unroll
    for (int q = 0; q < 4; ++q) {
#pragma unroll
      for (int r = 0; r < 16; ++r) {
        float val = acc[4 + q][r] + xch[0][q][r][lane];
        int c = (4 + q) * 32 + (r & 3) + 8 * (r >> 2) + 4 * hi;
        oc[(size_t)c * 4096] = g * (val * inv) + xc[(size_t)c * 4096];
      }
    }
  }
}

extern "C" void kernel_launch(void* const* d_in, const int* in_sizes, int n_in,
                              void* d_out, int out_size, void* d_ws, size_t ws_size,
                              hipStream_t stream) {
  const float* x  = (const float*)d_in[0];
  const float* Wq = (const float*)d_in[1];
  const float* bq = (const float*)d_in[2];
  const float* Wk = (const float*)d_in[3];
  const float* bk = (const float*)d_in[4];
  const float* Wv = (const float*)d_in[5];
  const float* bv = (const float*)d_in[6];
  const float* gm = (const float*)d_in[7];
  float* out = (float*)d_out;

  ushort* qs = (ushort*)d_ws;
  ushort* kzp = qs + (size_t)8 * 131072;
  ushort* vzp = kzp + (size_t)8 * 131072;

  proj_qkv<<<dim3(16, 8, 5), 256, 0, stream>>>(x, Wq, bq, Wk, bk, Wv, bv, qs, kzp, vzp);
  attn_fused<<<dim3(1024), 128, 0, stream>>>(qs, kzp, vzp, x, gm, out);
}